// Round 1
// baseline (790.265 us; speedup 1.0000x reference)
//
#include <hip/hip_runtime.h>
#include <hip/hip_bf16.h>

// Problem: B=4096, N=8192, D=1024
//   h = x*mask/0.75
//   enc = tanh(h @ W^T + b1)          GEMM1: [B,N]x[D,N]^T -> [B,D]
//   final = LN_D(enc)*gamma + beta    (output 0, B*D f32)
//   recon = enc @ W + b2              GEMM2: [B,D]x[D,N] -> [B,N] (not materialized)
//   loss = sum_b sum_n (nz*(x-recon))^2 / sum_n nz    (output 1, 1 f32)

#define Bdim 4096
#define Ndim 8192
#define Ddim 1024

typedef short short8 __attribute__((ext_vector_type(8)));
typedef float floatx4 __attribute__((ext_vector_type(4)));

__device__ __forceinline__ ushort f2bf(float f) {
    union { float f; unsigned int u; } v; v.f = f;
    unsigned int r = (v.u + 0x7FFFu + ((v.u >> 16) & 1u)) >> 16;
    return (ushort)r;
}
__device__ __forceinline__ float bf2f(ushort u) {
    union { unsigned int u; float f; } v; v.u = ((unsigned int)u) << 16;
    return v.f;
}
__device__ __forceinline__ unsigned int pk(ushort a, ushort b) {
    return (unsigned int)a | ((unsigned int)b << 16);
}

// ---------------- prep: h = bf16(x*mask/0.75) ----------------
__global__ void prep_h_kernel(const float* __restrict__ x, const float* __restrict__ mask,
                              ushort* __restrict__ h) {
    const float C = 1.0f / 0.75f;
    size_t i = ((size_t)blockIdx.x * 256 + threadIdx.x) * 8;
    float4 x0 = *(const float4*)&x[i];
    float4 x1 = *(const float4*)&x[i + 4];
    float4 m0 = *(const float4*)&mask[i];
    float4 m1 = *(const float4*)&mask[i + 4];
    uint4 o;
    o.x = pk(f2bf(x0.x * m0.x * C), f2bf(x0.y * m0.y * C));
    o.y = pk(f2bf(x0.z * m0.z * C), f2bf(x0.w * m0.w * C));
    o.z = pk(f2bf(x1.x * m1.x * C), f2bf(x1.y * m1.y * C));
    o.w = pk(f2bf(x1.z * m1.z * C), f2bf(x1.w * m1.w * C));
    *(uint4*)&h[i] = o;
}

// ---------------- prep: Wb = bf16(W), Wt = bf16(W^T) ----------------
__global__ void prep_w_kernel(const float* __restrict__ W, ushort* __restrict__ Wb,
                              ushort* __restrict__ Wt) {
    __shared__ float tl[64][65];
    int n0 = blockIdx.x * 64, d0 = blockIdx.y * 64;
    int tx = threadIdx.x, ty = threadIdx.y;  // 64 x 4
    for (int i = ty; i < 64; i += 4) {
        float v = W[(size_t)(d0 + i) * Ndim + n0 + tx];
        tl[i][tx] = v;
        Wb[(size_t)(d0 + i) * Ndim + n0 + tx] = f2bf(v);
    }
    __syncthreads();
    for (int i = ty; i < 64; i += 4)
        Wt[(size_t)(n0 + i) * Ddim + d0 + tx] = f2bf(tl[tx][i]);
}

// ---------------- GEMM1: enc = tanh(h @ W^T + b1), bf16 MFMA ----------------
// Tiles: BM=128, BN=64, BK=32. 256 threads = 4 waves in 2x2; wave tile 64x32.
__global__ void gemm1_kernel(const ushort* __restrict__ A,     // h bf16 [B][N] (fast path)
                             const float* __restrict__ x,      // conv path
                             const float* __restrict__ mask,   // conv path
                             const ushort* __restrict__ Wb,    // [D][N] bf16
                             const float* __restrict__ b1,
                             ushort* __restrict__ enc,         // [B][D] bf16
                             int conv) {
    const int K = Ndim;
    __shared__ __attribute__((aligned(16))) ushort As[128][32];
    __shared__ __attribute__((aligned(16))) ushort Bs[64][32];
    int m0 = blockIdx.y * 128, n0 = blockIdx.x * 64;
    int t = threadIdx.x;
    int lane = t & 63, w = t >> 6;
    int wm = w >> 1, wn = w & 1;
    int quad = lane >> 4, lrow = lane & 15;
    const float C = 1.0f / 0.75f;

    floatx4 acc[4][2];
    for (int i = 0; i < 4; i++) for (int j = 0; j < 2; j++) acc[i][j] = (floatx4)0.0f;

    for (int k0 = 0; k0 < K; k0 += 32) {
        // stage A: 128x32 bf16 (512 chunks of 8)
        if (!conv) {
            for (int c = t; c < 512; c += 256) {
                int r = c >> 2, cc = (c & 3) * 8;
                *(uint4*)&As[r][cc] = *(const uint4*)&A[(size_t)(m0 + r) * K + k0 + cc];
            }
        } else {
            for (int c = t; c < 512; c += 256) {
                int r = c >> 2, cc = (c & 3) * 8;
                const float* px = &x[(size_t)(m0 + r) * K + k0 + cc];
                const float* pm = &mask[(size_t)(m0 + r) * K + k0 + cc];
                float4 xa = *(const float4*)px, xb = *(const float4*)(px + 4);
                float4 ma = *(const float4*)pm, mb = *(const float4*)(pm + 4);
                uint4 o;
                o.x = pk(f2bf(xa.x * ma.x * C), f2bf(xa.y * ma.y * C));
                o.y = pk(f2bf(xa.z * ma.z * C), f2bf(xa.w * ma.w * C));
                o.z = pk(f2bf(xb.x * mb.x * C), f2bf(xb.y * mb.y * C));
                o.w = pk(f2bf(xb.z * mb.z * C), f2bf(xb.w * mb.w * C));
                *(uint4*)&As[r][cc] = o;
            }
        }
        // stage B: 64x32 bf16 (256 chunks)
        {
            int c = t;
            int r = c >> 2, cc = (c & 3) * 8;
            *(uint4*)&Bs[r][cc] = *(const uint4*)&Wb[(size_t)(n0 + r) * K + k0 + cc];
        }
        __syncthreads();
        short8 af[4], bfr[2];
        for (int i = 0; i < 4; i++) af[i] = *(const short8*)&As[wm * 64 + i * 16 + lrow][quad * 8];
        for (int j = 0; j < 2; j++) bfr[j] = *(const short8*)&Bs[wn * 32 + j * 16 + lrow][quad * 8];
        for (int i = 0; i < 4; i++)
            for (int j = 0; j < 2; j++)
                acc[i][j] = __builtin_amdgcn_mfma_f32_16x16x32_bf16(af[i], bfr[j], acc[i][j], 0, 0, 0);
        __syncthreads();
    }
    // epilogue: tanh(acc + b1) -> enc bf16
    for (int j = 0; j < 2; j++) {
        int col = n0 + wn * 32 + j * 16 + lrow;
        float bb = b1[col];
        for (int i = 0; i < 4; i++) {
            for (int r = 0; r < 4; r++) {
                int row = m0 + wm * 64 + i * 16 + quad * 4 + r;
                float v = tanhf(acc[i][j][r] + bb);
                enc[(size_t)row * Ddim + col] = f2bf(v);
            }
        }
    }
}

// ---------------- GEMM2: recon loss partials, bf16 MFMA ----------------
// Tiles: BM=128, BN=128, BK=32. 4 waves 2x2; wave tile 64x64.
__global__ void gemm2_kernel(const ushort* __restrict__ enc,  // [B][D] bf16
                             const ushort* __restrict__ Wt,   // [N][D] bf16
                             const float* __restrict__ b2,
                             const float* __restrict__ x,     // [B][N] f32
                             float* __restrict__ num, float* __restrict__ den) {
    const int K = Ddim;
    __shared__ __attribute__((aligned(16))) ushort As[128][32];
    __shared__ __attribute__((aligned(16))) ushort Bs[128][32];
    int m0 = blockIdx.y * 128, n0 = blockIdx.x * 128;
    int t = threadIdx.x;
    int lane = t & 63, w = t >> 6;
    int wm = w >> 1, wn = w & 1;
    int quad = lane >> 4, lrow = lane & 15;

    floatx4 acc[4][4];
    for (int i = 0; i < 4; i++) for (int j = 0; j < 4; j++) acc[i][j] = (floatx4)0.0f;

    for (int k0 = 0; k0 < K; k0 += 32) {
        for (int c = t; c < 512; c += 256) {
            int r = c >> 2, cc = (c & 3) * 8;
            *(uint4*)&As[r][cc] = *(const uint4*)&enc[(size_t)(m0 + r) * K + k0 + cc];
        }
        for (int c = t; c < 512; c += 256) {
            int r = c >> 2, cc = (c & 3) * 8;
            *(uint4*)&Bs[r][cc] = *(const uint4*)&Wt[(size_t)(n0 + r) * K + k0 + cc];
        }
        __syncthreads();
        short8 af[4], bfr[4];
        for (int i = 0; i < 4; i++) af[i] = *(const short8*)&As[wm * 64 + i * 16 + lrow][quad * 8];
        for (int j = 0; j < 4; j++) bfr[j] = *(const short8*)&Bs[wn * 64 + j * 16 + lrow][quad * 8];
        for (int i = 0; i < 4; i++)
            for (int j = 0; j < 4; j++)
                acc[i][j] = __builtin_amdgcn_mfma_f32_16x16x32_bf16(af[i], bfr[j], acc[i][j], 0, 0, 0);
        __syncthreads();
    }
    // epilogue: per-row sum of (x - (acc+b2))^2 over this block's 64-col slab per wave
    for (int i = 0; i < 4; i++) {
        for (int r = 0; r < 4; r++) {
            int row = m0 + wm * 64 + i * 16 + quad * 4 + r;
            float ns = 0.0f, ds = 0.0f;
            for (int j = 0; j < 4; j++) {
                int col = n0 + wn * 64 + j * 16 + lrow;
                float recon = acc[i][j][r] + b2[col];
                float xv = x[(size_t)row * Ndim + col];
                if (xv != 0.0f) {
                    float d = xv - recon;
                    ns += d * d;
                    ds += 1.0f;
                }
            }
            for (int s = 1; s < 16; s <<= 1) {
                ns += __shfl_xor(ns, s);
                ds += __shfl_xor(ds, s);
            }
            if (lrow == 0) {
                atomicAdd(&num[row], ns);
                atomicAdd(&den[row], ds);
            }
        }
    }
}

// ---------------- LayerNorm over D ----------------
__global__ void ln_kernel(const ushort* __restrict__ enc, const float* __restrict__ gamma,
                          const float* __restrict__ beta, float* __restrict__ out) {
    int row = blockIdx.x;
    int t = threadIdx.x;  // 256 threads, 4 elems each
    const ushort* e = &enc[(size_t)row * Ddim];
    uint2 u = *(const uint2*)&e[t * 4];
    float v0 = bf2f((ushort)(u.x & 0xFFFF)), v1 = bf2f((ushort)(u.x >> 16));
    float v2 = bf2f((ushort)(u.y & 0xFFFF)), v3 = bf2f((ushort)(u.y >> 16));
    float s = v0 + v1 + v2 + v3;
    float sq = v0 * v0 + v1 * v1 + v2 * v2 + v3 * v3;
    for (int sft = 1; sft < 64; sft <<= 1) {
        s += __shfl_xor(s, sft);
        sq += __shfl_xor(sq, sft);
    }
    __shared__ float red[8];
    int w = t >> 6, lane = t & 63;
    if (lane == 0) { red[w] = s; red[w + 4] = sq; }
    __syncthreads();
    s = red[0] + red[1] + red[2] + red[3];
    sq = red[4] + red[5] + red[6] + red[7];
    float mu = s * (1.0f / Ddim);
    float var = sq * (1.0f / Ddim) - mu * mu;
    float rstd = rsqrtf(var + 1e-5f);
    float4 g = *(const float4*)&gamma[t * 4];
    float4 b = *(const float4*)&beta[t * 4];
    float4 o;
    o.x = (v0 - mu) * rstd * g.x + b.x;
    o.y = (v1 - mu) * rstd * g.y + b.y;
    o.z = (v2 - mu) * rstd * g.z + b.z;
    o.w = (v3 - mu) * rstd * g.w + b.w;
    *(float4*)&out[(size_t)row * Ddim + t * 4] = o;
}

// ---------------- loss = sum_b num[b]/den[b] ----------------
__global__ void loss_final_kernel(const float* __restrict__ num, const float* __restrict__ den,
                                  float* __restrict__ out) {
    int t = threadIdx.x;  // 256
    float s = 0.0f;
    for (int i = t; i < Bdim; i += 256) s += num[i] / den[i];
    for (int sft = 1; sft < 64; sft <<= 1) s += __shfl_xor(s, sft);
    __shared__ float red[4];
    int w = t >> 6, lane = t & 63;
    if (lane == 0) red[w] = s;
    __syncthreads();
    if (t == 0) out[0] = red[0] + red[1] + red[2] + red[3];
}

// ---------------- workspace layout ----------------
#define WB_OFF   0ull
#define WB_SZ    ((size_t)Ddim * Ndim * 2)            // 16 MiB
#define WT_OFF   (WB_OFF + WB_SZ)
#define WT_SZ    ((size_t)Ndim * Ddim * 2)            // 16 MiB
#define ENC_OFF  (WT_OFF + WT_SZ)
#define ENC_SZ   ((size_t)Bdim * Ddim * 2)            // 8 MiB
#define NUM_OFF  (ENC_OFF + ENC_SZ)
#define NUM_SZ   ((size_t)Bdim * 4)
#define DEN_OFF  (NUM_OFF + NUM_SZ)
#define DEN_SZ   ((size_t)Bdim * 4)
#define H_OFF    (DEN_OFF + DEN_SZ)
#define H_SZ     ((size_t)Bdim * Ndim * 2)            // 64 MiB
#define FAST_NEED (H_OFF + H_SZ)

extern "C" void kernel_launch(void* const* d_in, const int* in_sizes, int n_in,
                              void* d_out, int out_size, void* d_ws, size_t ws_size,
                              hipStream_t stream) {
    const float* x     = (const float*)d_in[0];
    const float* mask  = (const float*)d_in[1];
    const float* W     = (const float*)d_in[2];
    const float* b1    = (const float*)d_in[3];
    const float* b2    = (const float*)d_in[4];
    const float* gamma = (const float*)d_in[5];
    const float* beta  = (const float*)d_in[6];

    float* final_out = (float*)d_out;                       // [B*D]
    float* loss_out  = final_out + (size_t)Bdim * Ddim;     // [1]

    char* ws = (char*)d_ws;
    ushort* Wb   = (ushort*)(ws + WB_OFF);
    ushort* Wt   = (ushort*)(ws + WT_OFF);
    ushort* enc  = (ushort*)(ws + ENC_OFF);
    float*  num  = (float*)(ws + NUM_OFF);
    float*  den  = (float*)(ws + DEN_OFF);
    ushort* hbuf = (ushort*)(ws + H_OFF);

    bool fast = ws_size >= FAST_NEED;

    hipMemsetAsync(num, 0, NUM_SZ + DEN_SZ, stream);

    prep_w_kernel<<<dim3(Ndim / 64, Ddim / 64), dim3(64, 4), 0, stream>>>(W, Wb, Wt);

    if (fast) {
        prep_h_kernel<<<(Bdim * (size_t)Ndim) / 8 / 256, 256, 0, stream>>>(x, mask, hbuf);
        gemm1_kernel<<<dim3(Ddim / 64, Bdim / 128), 256, 0, stream>>>(hbuf, x, mask, Wb, b1, enc, 0);
    } else {
        gemm1_kernel<<<dim3(Ddim / 64, Bdim / 128), 256, 0, stream>>>(nullptr, x, mask, Wb, b1, enc, 1);
    }

    ln_kernel<<<Bdim, 256, 0, stream>>>(enc, gamma, beta, final_out);

    gemm2_kernel<<<dim3(Ndim / 128, Bdim / 128), 256, 0, stream>>>(enc, Wt, b2, x, num, den);

    loss_final_kernel<<<1, 256, 0, stream>>>(num, den, loss_out);
}

// Round 2
// 629.568 us; speedup vs baseline: 1.2552x; 1.2552x over previous
//
#include <hip/hip_runtime.h>
#include <hip/hip_bf16.h>

// Problem: B=4096, N=8192, D=1024
//   h = x*mask/0.75
//   enc = tanh(h @ W^T + b1)          GEMM1: [B,N]x[D,N]^T -> [B,D]
//   final = LN_D(enc)*gamma + beta    (output 0, B*D f32)
//   recon = enc @ W + b2              GEMM2: [B,D]x[D,N] -> [B,N] (not materialized)
//   loss = sum_b sum_n (nz*(x-recon))^2 / sum_n nz    (output 1, 1 f32)

#define Bdim 4096
#define Ndim 8192
#define Ddim 1024

typedef short short8 __attribute__((ext_vector_type(8)));
typedef float floatx4 __attribute__((ext_vector_type(4)));

__device__ __forceinline__ ushort f2bf(float f) {
    union { float f; unsigned int u; } v; v.f = f;
    unsigned int r = (v.u + 0x7FFFu + ((v.u >> 16) & 1u)) >> 16;
    return (ushort)r;
}
__device__ __forceinline__ float bf2f(ushort u) {
    union { unsigned int u; float f; } v; v.u = ((unsigned int)u) << 16;
    return v.f;
}
__device__ __forceinline__ unsigned int pk(ushort a, ushort b) {
    return (unsigned int)a | ((unsigned int)b << 16);
}

// async global->LDS, 16B per lane. LDS dest is wave-uniform base + lane*16.
__device__ __forceinline__ void gl_lds16(const ushort* g, ushort* l) {
    __builtin_amdgcn_global_load_lds(
        (const __attribute__((address_space(1))) unsigned int*)g,
        (__attribute__((address_space(3))) unsigned int*)l,
        16, 0, 0);
}

// ---------------- prep: h = bf16(x*mask/0.75) ----------------
__global__ void prep_h_kernel(const float* __restrict__ x, const float* __restrict__ mask,
                              ushort* __restrict__ h) {
    const float C = 1.0f / 0.75f;
    size_t i = ((size_t)blockIdx.x * 256 + threadIdx.x) * 8;
    float4 x0 = *(const float4*)&x[i];
    float4 x1 = *(const float4*)&x[i + 4];
    float4 m0 = *(const float4*)&mask[i];
    float4 m1 = *(const float4*)&mask[i + 4];
    uint4 o;
    o.x = pk(f2bf(x0.x * m0.x * C), f2bf(x0.y * m0.y * C));
    o.y = pk(f2bf(x0.z * m0.z * C), f2bf(x0.w * m0.w * C));
    o.z = pk(f2bf(x1.x * m1.x * C), f2bf(x1.y * m1.y * C));
    o.w = pk(f2bf(x1.z * m1.z * C), f2bf(x1.w * m1.w * C));
    *(uint4*)&h[i] = o;
}

// ---------------- prep: Wb = bf16(W), Wt = bf16(W^T) ----------------
__global__ void prep_w_kernel(const float* __restrict__ W, ushort* __restrict__ Wb,
                              ushort* __restrict__ Wt) {
    __shared__ float tl[64][65];
    int n0 = blockIdx.x * 64, d0 = blockIdx.y * 64;
    int tx = threadIdx.x, ty = threadIdx.y;  // 64 x 4
    for (int i = ty; i < 64; i += 4) {
        float v = W[(size_t)(d0 + i) * Ndim + n0 + tx];
        tl[i][tx] = v;
        Wb[(size_t)(d0 + i) * Ndim + n0 + tx] = f2bf(v);
    }
    __syncthreads();
    for (int i = ty; i < 64; i += 4)
        Wt[(size_t)(n0 + i) * Ddim + d0 + tx] = f2bf(tl[tx][i]);
}

// ---------------- GEMM1: enc = tanh(h @ W^T + b1) ----------------
// BM=128, BN=64, BK=64. 256 threads = 4 waves 2x2; wave tile 64x32.
// global_load_lds staging with XOR bank-swizzle (cc ^= row&7).
__global__ void __launch_bounds__(256) gemm1_kernel(
        const ushort* __restrict__ A,    // h bf16 [B][N]
        const ushort* __restrict__ Wb,   // [D][N] bf16
        const float* __restrict__ b1,
        ushort* __restrict__ enc) {      // [B][D] bf16
    const int K = Ndim;
    __shared__ __attribute__((aligned(16))) ushort As[128][64];  // 16 KB
    __shared__ __attribute__((aligned(16))) ushort Bs[64][64];   // 8 KB
    int m0 = blockIdx.y * 128, n0 = blockIdx.x * 64;
    int t = threadIdx.x;
    int lane = t & 63, w = t >> 6;
    int wm = w >> 1, wn = w & 1;
    int quad = lane >> 4, lrow = lane & 15;

    ushort* AsF = &As[0][0];
    ushort* BsF = &Bs[0][0];
    int wofs = (t & 192) * 8;  // wave-uniform chunk base (ushorts)

    floatx4 acc[4][2];
    for (int i = 0; i < 4; i++) for (int j = 0; j < 2; j++) acc[i][j] = (floatx4)0.0f;

    for (int k0 = 0; k0 < K; k0 += 64) {
        // stage A: 128x64 = 1024 chunks of 16B, 4 passes
        #pragma unroll
        for (int p = 0; p < 4; p++) {
            int c = p * 256 + t;
            int r = c >> 3, cc = c & 7;
            int g = cc ^ (r & 7);
            gl_lds16(&A[(size_t)(m0 + r) * K + k0 + g * 8], AsF + p * 2048 + wofs);
        }
        // stage B: 64x64 = 512 chunks, 2 passes
        #pragma unroll
        for (int p = 0; p < 2; p++) {
            int c = p * 256 + t;
            int r = c >> 3, cc = c & 7;
            int g = cc ^ (r & 7);
            gl_lds16(&Wb[(size_t)(n0 + r) * K + k0 + g * 8], BsF + p * 2048 + wofs);
        }
        __syncthreads();
        short8 af[2][4], bfr[2][2];
        #pragma unroll
        for (int k1 = 0; k1 < 2; k1++) {
            #pragma unroll
            for (int i = 0; i < 4; i++) {
                int r = wm * 64 + i * 16 + lrow;
                int q = (k1 * 4 + quad) ^ (r & 7);
                af[k1][i] = *(const short8*)&As[r][q * 8];
            }
            #pragma unroll
            for (int j = 0; j < 2; j++) {
                int r = wn * 32 + j * 16 + lrow;
                int q = (k1 * 4 + quad) ^ (r & 7);
                bfr[k1][j] = *(const short8*)&Bs[r][q * 8];
            }
        }
        #pragma unroll
        for (int k1 = 0; k1 < 2; k1++)
            #pragma unroll
            for (int i = 0; i < 4; i++)
                #pragma unroll
                for (int j = 0; j < 2; j++)
                    acc[i][j] = __builtin_amdgcn_mfma_f32_16x16x32_bf16(af[k1][i], bfr[k1][j], acc[i][j], 0, 0, 0);
        __syncthreads();
    }
    // epilogue: tanh(acc + b1) -> enc bf16
    for (int j = 0; j < 2; j++) {
        int col = n0 + wn * 32 + j * 16 + lrow;
        float bb = b1[col];
        for (int i = 0; i < 4; i++) {
            for (int r = 0; r < 4; r++) {
                int row = m0 + wm * 64 + i * 16 + quad * 4 + r;
                float v = tanhf(acc[i][j][r] + bb);
                enc[(size_t)row * Ddim + col] = f2bf(v);
            }
        }
    }
}

// ---------------- GEMM1 fallback (ws too small): convert x*mask in-staging ----------------
__global__ void gemm1_conv_kernel(const float* __restrict__ x, const float* __restrict__ mask,
                                  const ushort* __restrict__ Wb, const float* __restrict__ b1,
                                  ushort* __restrict__ enc) {
    const int K = Ndim;
    __shared__ __attribute__((aligned(16))) ushort As[128][32];
    __shared__ __attribute__((aligned(16))) ushort Bs[64][32];
    int m0 = blockIdx.y * 128, n0 = blockIdx.x * 64;
    int t = threadIdx.x;
    int lane = t & 63, w = t >> 6;
    int wm = w >> 1, wn = w & 1;
    int quad = lane >> 4, lrow = lane & 15;
    const float C = 1.0f / 0.75f;

    floatx4 acc[4][2];
    for (int i = 0; i < 4; i++) for (int j = 0; j < 2; j++) acc[i][j] = (floatx4)0.0f;

    for (int k0 = 0; k0 < K; k0 += 32) {
        for (int c = t; c < 512; c += 256) {
            int r = c >> 2, cc = (c & 3) * 8;
            const float* px = &x[(size_t)(m0 + r) * K + k0 + cc];
            const float* pm = &mask[(size_t)(m0 + r) * K + k0 + cc];
            float4 xa = *(const float4*)px, xb = *(const float4*)(px + 4);
            float4 ma = *(const float4*)pm, mb = *(const float4*)(pm + 4);
            uint4 o;
            o.x = pk(f2bf(xa.x * ma.x * C), f2bf(xa.y * ma.y * C));
            o.y = pk(f2bf(xa.z * ma.z * C), f2bf(xa.w * ma.w * C));
            o.z = pk(f2bf(xb.x * mb.x * C), f2bf(xb.y * mb.y * C));
            o.w = pk(f2bf(xb.z * mb.z * C), f2bf(xb.w * mb.w * C));
            *(uint4*)&As[r][cc] = o;
        }
        {
            int c = t;
            int r = c >> 2, cc = (c & 3) * 8;
            *(uint4*)&Bs[r][cc] = *(const uint4*)&Wb[(size_t)(n0 + r) * K + k0 + cc];
        }
        __syncthreads();
        short8 af[4], bfr[2];
        for (int i = 0; i < 4; i++) af[i] = *(const short8*)&As[wm * 64 + i * 16 + lrow][quad * 8];
        for (int j = 0; j < 2; j++) bfr[j] = *(const short8*)&Bs[wn * 32 + j * 16 + lrow][quad * 8];
        for (int i = 0; i < 4; i++)
            for (int j = 0; j < 2; j++)
                acc[i][j] = __builtin_amdgcn_mfma_f32_16x16x32_bf16(af[i], bfr[j], acc[i][j], 0, 0, 0);
        __syncthreads();
    }
    for (int j = 0; j < 2; j++) {
        int col = n0 + wn * 32 + j * 16 + lrow;
        float bb = b1[col];
        for (int i = 0; i < 4; i++) {
            for (int r = 0; r < 4; r++) {
                int row = m0 + wm * 64 + i * 16 + quad * 4 + r;
                float v = tanhf(acc[i][j][r] + bb);
                enc[(size_t)row * Ddim + col] = f2bf(v);
            }
        }
    }
}

// ---------------- GEMM2: recon loss partials ----------------
// BM=128, BN=128, BK=32 (m97 structure). 4 waves 2x2; wave tile 64x64.
// global_load_lds staging with XOR bank-swizzle (cc ^= (row>>1)&3).
__global__ void __launch_bounds__(256) gemm2_kernel(
        const ushort* __restrict__ enc,  // [B][D] bf16
        const ushort* __restrict__ Wt,   // [N][D] bf16
        const float* __restrict__ b2,
        const float* __restrict__ x,     // [B][N] f32
        float* __restrict__ num, float* __restrict__ den) {
    const int K = Ddim;
    __shared__ __attribute__((aligned(16))) ushort As[128][32];  // 8 KB
    __shared__ __attribute__((aligned(16))) ushort Bs[128][32];  // 8 KB
    int m0 = blockIdx.y * 128, n0 = blockIdx.x * 128;
    int t = threadIdx.x;
    int lane = t & 63, w = t >> 6;
    int wm = w >> 1, wn = w & 1;
    int quad = lane >> 4, lrow = lane & 15;

    ushort* AsF = &As[0][0];
    ushort* BsF = &Bs[0][0];
    int wofs = (t & 192) * 8;

    floatx4 acc[4][4];
    for (int i = 0; i < 4; i++) for (int j = 0; j < 4; j++) acc[i][j] = (floatx4)0.0f;

    for (int k0 = 0; k0 < K; k0 += 32) {
        #pragma unroll
        for (int p = 0; p < 2; p++) {
            int c = p * 256 + t;
            int r = c >> 2, cc = c & 3;
            int g = cc ^ ((r >> 1) & 3);
            gl_lds16(&enc[(size_t)(m0 + r) * K + k0 + g * 8], AsF + p * 2048 + wofs);
        }
        #pragma unroll
        for (int p = 0; p < 2; p++) {
            int c = p * 256 + t;
            int r = c >> 2, cc = c & 3;
            int g = cc ^ ((r >> 1) & 3);
            gl_lds16(&Wt[(size_t)(n0 + r) * K + k0 + g * 8], BsF + p * 2048 + wofs);
        }
        __syncthreads();
        short8 af[4], bfr[4];
        #pragma unroll
        for (int i = 0; i < 4; i++) {
            int r = wm * 64 + i * 16 + lrow;
            int q = quad ^ ((r >> 1) & 3);
            af[i] = *(const short8*)&As[r][q * 8];
        }
        #pragma unroll
        for (int j = 0; j < 4; j++) {
            int r = wn * 64 + j * 16 + lrow;
            int q = quad ^ ((r >> 1) & 3);
            bfr[j] = *(const short8*)&Bs[r][q * 8];
        }
        #pragma unroll
        for (int i = 0; i < 4; i++)
            #pragma unroll
            for (int j = 0; j < 4; j++)
                acc[i][j] = __builtin_amdgcn_mfma_f32_16x16x32_bf16(af[i], bfr[j], acc[i][j], 0, 0, 0);
        __syncthreads();
    }
    // epilogue: per-row sum of (x - (acc+b2))^2
    for (int i = 0; i < 4; i++) {
        for (int r = 0; r < 4; r++) {
            int row = m0 + wm * 64 + i * 16 + quad * 4 + r;
            float ns = 0.0f, ds = 0.0f;
            for (int j = 0; j < 4; j++) {
                int col = n0 + wn * 64 + j * 16 + lrow;
                float recon = acc[i][j][r] + b2[col];
                float xv = x[(size_t)row * Ndim + col];
                if (xv != 0.0f) {
                    float d = xv - recon;
                    ns += d * d;
                    ds += 1.0f;
                }
            }
            for (int s = 1; s < 16; s <<= 1) {
                ns += __shfl_xor(ns, s);
                ds += __shfl_xor(ds, s);
            }
            if (lrow == 0) {
                atomicAdd(&num[row], ns);
                atomicAdd(&den[row], ds);
            }
        }
    }
}

// ---------------- LayerNorm over D ----------------
__global__ void ln_kernel(const ushort* __restrict__ enc, const float* __restrict__ gamma,
                          const float* __restrict__ beta, float* __restrict__ out) {
    int row = blockIdx.x;
    int t = threadIdx.x;  // 256 threads, 4 elems each
    const ushort* e = &enc[(size_t)row * Ddim];
    uint2 u = *(const uint2*)&e[t * 4];
    float v0 = bf2f((ushort)(u.x & 0xFFFF)), v1 = bf2f((ushort)(u.x >> 16));
    float v2 = bf2f((ushort)(u.y & 0xFFFF)), v3 = bf2f((ushort)(u.y >> 16));
    float s = v0 + v1 + v2 + v3;
    float sq = v0 * v0 + v1 * v1 + v2 * v2 + v3 * v3;
    for (int sft = 1; sft < 64; sft <<= 1) {
        s += __shfl_xor(s, sft);
        sq += __shfl_xor(sq, sft);
    }
    __shared__ float red[8];
    int w = t >> 6, lane = t & 63;
    if (lane == 0) { red[w] = s; red[w + 4] = sq; }
    __syncthreads();
    s = red[0] + red[1] + red[2] + red[3];
    sq = red[4] + red[5] + red[6] + red[7];
    float mu = s * (1.0f / Ddim);
    float var = sq * (1.0f / Ddim) - mu * mu;
    float rstd = rsqrtf(var + 1e-5f);
    float4 g = *(const float4*)&gamma[t * 4];
    float4 b = *(const float4*)&beta[t * 4];
    float4 o;
    o.x = (v0 - mu) * rstd * g.x + b.x;
    o.y = (v1 - mu) * rstd * g.y + b.y;
    o.z = (v2 - mu) * rstd * g.z + b.z;
    o.w = (v3 - mu) * rstd * g.w + b.w;
    *(float4*)&out[(size_t)row * Ddim + t * 4] = o;
}

// ---------------- loss = sum_b num[b]/den[b] ----------------
__global__ void loss_final_kernel(const float* __restrict__ num, const float* __restrict__ den,
                                  float* __restrict__ out) {
    int t = threadIdx.x;  // 256
    float s = 0.0f;
    for (int i = t; i < Bdim; i += 256) s += num[i] / den[i];
    for (int sft = 1; sft < 64; sft <<= 1) s += __shfl_xor(s, sft);
    __shared__ float red[4];
    int w = t >> 6, lane = t & 63;
    if (lane == 0) red[w] = s;
    __syncthreads();
    if (t == 0) out[0] = red[0] + red[1] + red[2] + red[3];
}

// ---------------- workspace layout ----------------
#define WB_OFF   0ull
#define WB_SZ    ((size_t)Ddim * Ndim * 2)            // 16 MiB
#define WT_OFF   (WB_OFF + WB_SZ)
#define WT_SZ    ((size_t)Ndim * Ddim * 2)            // 16 MiB
#define ENC_OFF  (WT_OFF + WT_SZ)
#define ENC_SZ   ((size_t)Bdim * Ddim * 2)            // 8 MiB
#define NUM_OFF  (ENC_OFF + ENC_SZ)
#define NUM_SZ   ((size_t)Bdim * 4)
#define DEN_OFF  (NUM_OFF + NUM_SZ)
#define DEN_SZ   ((size_t)Bdim * 4)
#define H_OFF    (DEN_OFF + DEN_SZ)
#define H_SZ     ((size_t)Bdim * Ndim * 2)            // 64 MiB
#define FAST_NEED (H_OFF + H_SZ)

extern "C" void kernel_launch(void* const* d_in, const int* in_sizes, int n_in,
                              void* d_out, int out_size, void* d_ws, size_t ws_size,
                              hipStream_t stream) {
    const float* x     = (const float*)d_in[0];
    const float* mask  = (const float*)d_in[1];
    const float* W     = (const float*)d_in[2];
    const float* b1    = (const float*)d_in[3];
    const float* b2    = (const float*)d_in[4];
    const float* gamma = (const float*)d_in[5];
    const float* beta  = (const float*)d_in[6];

    float* final_out = (float*)d_out;                       // [B*D]
    float* loss_out  = final_out + (size_t)Bdim * Ddim;     // [1]

    char* ws = (char*)d_ws;
    ushort* Wb   = (ushort*)(ws + WB_OFF);
    ushort* Wt   = (ushort*)(ws + WT_OFF);
    ushort* enc  = (ushort*)(ws + ENC_OFF);
    float*  num  = (float*)(ws + NUM_OFF);
    float*  den  = (float*)(ws + DEN_OFF);
    ushort* hbuf = (ushort*)(ws + H_OFF);

    bool fast = ws_size >= FAST_NEED;

    hipMemsetAsync(num, 0, NUM_SZ + DEN_SZ, stream);

    prep_w_kernel<<<dim3(Ndim / 64, Ddim / 64), dim3(64, 4), 0, stream>>>(W, Wb, Wt);

    if (fast) {
        prep_h_kernel<<<(Bdim * (size_t)Ndim) / 8 / 256, 256, 0, stream>>>(x, mask, hbuf);
        gemm1_kernel<<<dim3(Ddim / 64, Bdim / 128), 256, 0, stream>>>(hbuf, Wb, b1, enc);
    } else {
        gemm1_conv_kernel<<<dim3(Ddim / 64, Bdim / 128), 256, 0, stream>>>(x, mask, Wb, b1, enc);
    }

    ln_kernel<<<Bdim, 256, 0, stream>>>(enc, gamma, beta, final_out);

    gemm2_kernel<<<dim3(Ndim / 128, Bdim / 128), 256, 0, stream>>>(enc, Wt, b2, x, num, den);

    loss_final_kernel<<<1, 256, 0, stream>>>(num, den, loss_out);
}

// Round 3
// 624.807 us; speedup vs baseline: 1.2648x; 1.0076x over previous
//
#include <hip/hip_runtime.h>
#include <hip/hip_bf16.h>

// Problem: B=4096, N=8192, D=1024
//   h = x*mask/0.75
//   enc = tanh(h @ W^T + b1)          GEMM1: [B,N]x[D,N]^T -> [B,D]  (split-K=4)
//   final = LN_D(enc)*gamma + beta    (output 0, B*D f32)
//   recon = enc @ W + b2              GEMM2: [B,D]x[D,N] -> [B,N] (not materialized)
//   loss = sum_b sum_n (nz*(x-recon))^2 / sum_n nz    (output 1, 1 f32)

#define Bdim 4096
#define Ndim 8192
#define Ddim 1024
#define SPLITK 4
#define KC (Ndim / SPLITK)   // 2048

typedef short short8 __attribute__((ext_vector_type(8)));
typedef float floatx4 __attribute__((ext_vector_type(4)));

__device__ __forceinline__ ushort f2bf(float f) {
    union { float f; unsigned int u; } v; v.f = f;
    unsigned int r = (v.u + 0x7FFFu + ((v.u >> 16) & 1u)) >> 16;
    return (ushort)r;
}
__device__ __forceinline__ float bf2f(ushort u) {
    union { unsigned int u; float f; } v; v.u = ((unsigned int)u) << 16;
    return v.f;
}
__device__ __forceinline__ unsigned int pk(ushort a, ushort b) {
    return (unsigned int)a | ((unsigned int)b << 16);
}

// async global->LDS, 16B per lane. LDS dest is wave-uniform base + lane*16.
__device__ __forceinline__ void gl_lds16(const ushort* g, ushort* l) {
    __builtin_amdgcn_global_load_lds(
        (const __attribute__((address_space(1))) unsigned int*)g,
        (__attribute__((address_space(3))) unsigned int*)l,
        16, 0, 0);
}

// ---------------- prep: h = bf16(x*mask/0.75) ----------------
__global__ void prep_h_kernel(const float* __restrict__ x, const float* __restrict__ mask,
                              ushort* __restrict__ h) {
    const float C = 1.0f / 0.75f;
    size_t i = ((size_t)blockIdx.x * 256 + threadIdx.x) * 8;
    float4 x0 = *(const float4*)&x[i];
    float4 x1 = *(const float4*)&x[i + 4];
    float4 m0 = *(const float4*)&mask[i];
    float4 m1 = *(const float4*)&mask[i + 4];
    uint4 o;
    o.x = pk(f2bf(x0.x * m0.x * C), f2bf(x0.y * m0.y * C));
    o.y = pk(f2bf(x0.z * m0.z * C), f2bf(x0.w * m0.w * C));
    o.z = pk(f2bf(x1.x * m1.x * C), f2bf(x1.y * m1.y * C));
    o.w = pk(f2bf(x1.z * m1.z * C), f2bf(x1.w * m1.w * C));
    *(uint4*)&h[i] = o;
}

// ---------------- prep: Wb = bf16(W), Wt = bf16(W^T) ----------------
__global__ void prep_w_kernel(const float* __restrict__ W, ushort* __restrict__ Wb,
                              ushort* __restrict__ Wt) {
    __shared__ float tl[64][65];
    int n0 = blockIdx.x * 64, d0 = blockIdx.y * 64;
    int tx = threadIdx.x, ty = threadIdx.y;  // 64 x 4
    for (int i = ty; i < 64; i += 4) {
        float v = W[(size_t)(d0 + i) * Ndim + n0 + tx];
        tl[i][tx] = v;
        Wb[(size_t)(d0 + i) * Ndim + n0 + tx] = f2bf(v);
    }
    __syncthreads();
    for (int i = ty; i < 64; i += 4)
        Wt[(size_t)(n0 + i) * Ddim + d0 + tx] = f2bf(tl[tx][i]);
}

// ---------------- GEMM1 split-K: part[kc] = h_chunk @ W_chunk^T ----------------
// BM=128, BN=128, BK=64, K-chunk 2048. 4 waves 2x2; wave tile 64x64.
__global__ void __launch_bounds__(256) gemm1_sk_kernel(
        const ushort* __restrict__ A,    // h bf16 [B][N]
        const ushort* __restrict__ Wb,   // [D][N] bf16
        float* __restrict__ part) {      // [SPLITK][B][D] f32
    const int K = Ndim;
    __shared__ __attribute__((aligned(16))) ushort As[128][64];  // 16 KB
    __shared__ __attribute__((aligned(16))) ushort Bs[128][64];  // 16 KB
    int n0 = blockIdx.x * 128, m0 = blockIdx.y * 128;
    int kb0 = blockIdx.z * KC;
    int t = threadIdx.x;
    int lane = t & 63, w = t >> 6;
    int wm = w >> 1, wn = w & 1;
    int quad = lane >> 4, lrow = lane & 15;

    ushort* AsF = &As[0][0];
    ushort* BsF = &Bs[0][0];
    int wofs = (t & 192) * 8;  // wave-uniform chunk base (ushorts)

    floatx4 acc[4][4];
    for (int i = 0; i < 4; i++) for (int j = 0; j < 4; j++) acc[i][j] = (floatx4)0.0f;

    for (int k0 = kb0; k0 < kb0 + KC; k0 += 64) {
        // stage A: 128x64 = 1024 chunks of 16B, 4 passes
        #pragma unroll
        for (int p = 0; p < 4; p++) {
            int c = p * 256 + t;
            int r = c >> 3, cc = c & 7;
            int g = cc ^ (r & 7);
            gl_lds16(&A[(size_t)(m0 + r) * K + k0 + g * 8], AsF + p * 2048 + wofs);
        }
        // stage B: 128x64 = 1024 chunks, 4 passes
        #pragma unroll
        for (int p = 0; p < 4; p++) {
            int c = p * 256 + t;
            int r = c >> 3, cc = c & 7;
            int g = cc ^ (r & 7);
            gl_lds16(&Wb[(size_t)(n0 + r) * K + k0 + g * 8], BsF + p * 2048 + wofs);
        }
        __syncthreads();
        short8 af[2][4], bfr[2][4];
        #pragma unroll
        for (int k1 = 0; k1 < 2; k1++) {
            #pragma unroll
            for (int i = 0; i < 4; i++) {
                int r = wm * 64 + i * 16 + lrow;
                int q = (k1 * 4 + quad) ^ (r & 7);
                af[k1][i] = *(const short8*)&As[r][q * 8];
            }
            #pragma unroll
            for (int j = 0; j < 4; j++) {
                int r = wn * 64 + j * 16 + lrow;
                int q = (k1 * 4 + quad) ^ (r & 7);
                bfr[k1][j] = *(const short8*)&Bs[r][q * 8];
            }
        }
        #pragma unroll
        for (int k1 = 0; k1 < 2; k1++)
            #pragma unroll
            for (int i = 0; i < 4; i++)
                #pragma unroll
                for (int j = 0; j < 4; j++)
                    acc[i][j] = __builtin_amdgcn_mfma_f32_16x16x32_bf16(af[k1][i], bfr[k1][j], acc[i][j], 0, 0, 0);
        __syncthreads();
    }
    // epilogue: write f32 partials
    float* pb = &part[(size_t)blockIdx.z * Bdim * Ddim];
    for (int i = 0; i < 4; i++) {
        for (int r = 0; r < 4; r++) {
            int row = m0 + wm * 64 + i * 16 + quad * 4 + r;
            for (int j = 0; j < 4; j++) {
                int col = n0 + wn * 64 + j * 16 + lrow;
                pb[(size_t)row * Ddim + col] = acc[i][j][r];
            }
        }
    }
}

// ---------------- reduce partials + b1 + tanh -> enc; fused LayerNorm -> final ----------------
__global__ void reduce_ln_kernel(const float* __restrict__ part, const float* __restrict__ b1,
                                 const float* __restrict__ gamma, const float* __restrict__ beta,
                                 ushort* __restrict__ enc, float* __restrict__ out) {
    int row = blockIdx.x;
    int t = threadIdx.x;  // 256 threads, 4 elems each
    size_t base = (size_t)row * Ddim + t * 4;
    float4 v = *(const float4*)&part[base];
    #pragma unroll
    for (int kc = 1; kc < SPLITK; kc++) {
        float4 p = *(const float4*)&part[(size_t)kc * Bdim * Ddim + base];
        v.x += p.x; v.y += p.y; v.z += p.z; v.w += p.w;
    }
    float4 bb = *(const float4*)&b1[t * 4];
    float v0 = tanhf(v.x + bb.x), v1 = tanhf(v.y + bb.y);
    float v2 = tanhf(v.z + bb.z), v3 = tanhf(v.w + bb.w);
    // store enc as bf16 (input to GEMM2)
    uint2 eo;
    eo.x = pk(f2bf(v0), f2bf(v1));
    eo.y = pk(f2bf(v2), f2bf(v3));
    *(uint2*)&enc[base] = eo;
    // layernorm over D=1024
    float s = v0 + v1 + v2 + v3;
    float sq = v0 * v0 + v1 * v1 + v2 * v2 + v3 * v3;
    for (int sft = 1; sft < 64; sft <<= 1) {
        s += __shfl_xor(s, sft);
        sq += __shfl_xor(sq, sft);
    }
    __shared__ float red[8];
    int w = t >> 6, lane = t & 63;
    if (lane == 0) { red[w] = s; red[w + 4] = sq; }
    __syncthreads();
    s = red[0] + red[1] + red[2] + red[3];
    sq = red[4] + red[5] + red[6] + red[7];
    float mu = s * (1.0f / Ddim);
    float var = sq * (1.0f / Ddim) - mu * mu;
    float rstd = rsqrtf(var + 1e-5f);
    float4 g = *(const float4*)&gamma[t * 4];
    float4 b = *(const float4*)&beta[t * 4];
    float4 o;
    o.x = (v0 - mu) * rstd * g.x + b.x;
    o.y = (v1 - mu) * rstd * g.y + b.y;
    o.z = (v2 - mu) * rstd * g.z + b.z;
    o.w = (v3 - mu) * rstd * g.w + b.w;
    *(float4*)&out[base] = o;
}

// ---------------- GEMM1 fallback (no split-K ws): BM=128,BN=64,BK=64 ----------------
__global__ void __launch_bounds__(256) gemm1_kernel(
        const ushort* __restrict__ A, const ushort* __restrict__ Wb,
        const float* __restrict__ b1, ushort* __restrict__ enc) {
    const int K = Ndim;
    __shared__ __attribute__((aligned(16))) ushort As[128][64];
    __shared__ __attribute__((aligned(16))) ushort Bs[64][64];
    int m0 = blockIdx.y * 128, n0 = blockIdx.x * 64;
    int t = threadIdx.x;
    int lane = t & 63, w = t >> 6;
    int wm = w >> 1, wn = w & 1;
    int quad = lane >> 4, lrow = lane & 15;
    ushort* AsF = &As[0][0];
    ushort* BsF = &Bs[0][0];
    int wofs = (t & 192) * 8;

    floatx4 acc[4][2];
    for (int i = 0; i < 4; i++) for (int j = 0; j < 2; j++) acc[i][j] = (floatx4)0.0f;

    for (int k0 = 0; k0 < K; k0 += 64) {
        #pragma unroll
        for (int p = 0; p < 4; p++) {
            int c = p * 256 + t;
            int r = c >> 3, cc = c & 7;
            int g = cc ^ (r & 7);
            gl_lds16(&A[(size_t)(m0 + r) * K + k0 + g * 8], AsF + p * 2048 + wofs);
        }
        #pragma unroll
        for (int p = 0; p < 2; p++) {
            int c = p * 256 + t;
            int r = c >> 3, cc = c & 7;
            int g = cc ^ (r & 7);
            gl_lds16(&Wb[(size_t)(n0 + r) * K + k0 + g * 8], BsF + p * 2048 + wofs);
        }
        __syncthreads();
        short8 af[2][4], bfr[2][2];
        #pragma unroll
        for (int k1 = 0; k1 < 2; k1++) {
            #pragma unroll
            for (int i = 0; i < 4; i++) {
                int r = wm * 64 + i * 16 + lrow;
                int q = (k1 * 4 + quad) ^ (r & 7);
                af[k1][i] = *(const short8*)&As[r][q * 8];
            }
            #pragma unroll
            for (int j = 0; j < 2; j++) {
                int r = wn * 32 + j * 16 + lrow;
                int q = (k1 * 4 + quad) ^ (r & 7);
                bfr[k1][j] = *(const short8*)&Bs[r][q * 8];
            }
        }
        #pragma unroll
        for (int k1 = 0; k1 < 2; k1++)
            #pragma unroll
            for (int i = 0; i < 4; i++)
                #pragma unroll
                for (int j = 0; j < 2; j++)
                    acc[i][j] = __builtin_amdgcn_mfma_f32_16x16x32_bf16(af[k1][i], bfr[k1][j], acc[i][j], 0, 0, 0);
        __syncthreads();
    }
    for (int j = 0; j < 2; j++) {
        int col = n0 + wn * 32 + j * 16 + lrow;
        float bb = b1[col];
        for (int i = 0; i < 4; i++) {
            for (int r = 0; r < 4; r++) {
                int row = m0 + wm * 64 + i * 16 + quad * 4 + r;
                float v = tanhf(acc[i][j][r] + bb);
                enc[(size_t)row * Ddim + col] = f2bf(v);
            }
        }
    }
}

// ---------------- GEMM1 fallback (ws too small): convert x*mask in-staging ----------------
__global__ void gemm1_conv_kernel(const float* __restrict__ x, const float* __restrict__ mask,
                                  const ushort* __restrict__ Wb, const float* __restrict__ b1,
                                  ushort* __restrict__ enc) {
    const int K = Ndim;
    __shared__ __attribute__((aligned(16))) ushort As[128][32];
    __shared__ __attribute__((aligned(16))) ushort Bs[64][32];
    int m0 = blockIdx.y * 128, n0 = blockIdx.x * 64;
    int t = threadIdx.x;
    int lane = t & 63, w = t >> 6;
    int wm = w >> 1, wn = w & 1;
    int quad = lane >> 4, lrow = lane & 15;
    const float C = 1.0f / 0.75f;

    floatx4 acc[4][2];
    for (int i = 0; i < 4; i++) for (int j = 0; j < 2; j++) acc[i][j] = (floatx4)0.0f;

    for (int k0 = 0; k0 < K; k0 += 32) {
        for (int c = t; c < 512; c += 256) {
            int r = c >> 2, cc = (c & 3) * 8;
            const float* px = &x[(size_t)(m0 + r) * K + k0 + cc];
            const float* pm = &mask[(size_t)(m0 + r) * K + k0 + cc];
            float4 xa = *(const float4*)px, xb = *(const float4*)(px + 4);
            float4 ma = *(const float4*)pm, mb = *(const float4*)(pm + 4);
            uint4 o;
            o.x = pk(f2bf(xa.x * ma.x * C), f2bf(xa.y * ma.y * C));
            o.y = pk(f2bf(xa.z * ma.z * C), f2bf(xa.w * ma.w * C));
            o.z = pk(f2bf(xb.x * mb.x * C), f2bf(xb.y * mb.y * C));
            o.w = pk(f2bf(xb.z * mb.z * C), f2bf(xb.w * mb.w * C));
            *(uint4*)&As[r][cc] = o;
        }
        {
            int c = t;
            int r = c >> 2, cc = (c & 3) * 8;
            *(uint4*)&Bs[r][cc] = *(const uint4*)&Wb[(size_t)(n0 + r) * K + k0 + cc];
        }
        __syncthreads();
        short8 af[4], bfr[2];
        for (int i = 0; i < 4; i++) af[i] = *(const short8*)&As[wm * 64 + i * 16 + lrow][quad * 8];
        for (int j = 0; j < 2; j++) bfr[j] = *(const short8*)&Bs[wn * 32 + j * 16 + lrow][quad * 8];
        for (int i = 0; i < 4; i++)
            for (int j = 0; j < 2; j++)
                acc[i][j] = __builtin_amdgcn_mfma_f32_16x16x32_bf16(af[i], bfr[j], acc[i][j], 0, 0, 0);
        __syncthreads();
    }
    for (int j = 0; j < 2; j++) {
        int col = n0 + wn * 32 + j * 16 + lrow;
        float bb = b1[col];
        for (int i = 0; i < 4; i++) {
            for (int r = 0; r < 4; r++) {
                int row = m0 + wm * 64 + i * 16 + quad * 4 + r;
                float v = tanhf(acc[i][j][r] + bb);
                enc[(size_t)row * Ddim + col] = f2bf(v);
            }
        }
    }
}

// ---------------- GEMM2: recon loss partials ----------------
// BM=128, BN=128, BK=64. 4 waves 2x2; wave tile 64x64.
__global__ void __launch_bounds__(256) gemm2_kernel(
        const ushort* __restrict__ enc,  // [B][D] bf16
        const ushort* __restrict__ Wt,   // [N][D] bf16
        const float* __restrict__ b2,
        const float* __restrict__ x,     // [B][N] f32
        float* __restrict__ num, float* __restrict__ den) {
    const int K = Ddim;
    __shared__ __attribute__((aligned(16))) ushort As[128][64];  // 16 KB
    __shared__ __attribute__((aligned(16))) ushort Bs[128][64];  // 16 KB
    int m0 = blockIdx.y * 128, n0 = blockIdx.x * 128;
    int t = threadIdx.x;
    int lane = t & 63, w = t >> 6;
    int wm = w >> 1, wn = w & 1;
    int quad = lane >> 4, lrow = lane & 15;

    ushort* AsF = &As[0][0];
    ushort* BsF = &Bs[0][0];
    int wofs = (t & 192) * 8;

    floatx4 acc[4][4];
    for (int i = 0; i < 4; i++) for (int j = 0; j < 4; j++) acc[i][j] = (floatx4)0.0f;

    for (int k0 = 0; k0 < K; k0 += 64) {
        #pragma unroll
        for (int p = 0; p < 4; p++) {
            int c = p * 256 + t;
            int r = c >> 3, cc = c & 7;
            int g = cc ^ (r & 7);
            gl_lds16(&enc[(size_t)(m0 + r) * K + k0 + g * 8], AsF + p * 2048 + wofs);
        }
        #pragma unroll
        for (int p = 0; p < 4; p++) {
            int c = p * 256 + t;
            int r = c >> 3, cc = c & 7;
            int g = cc ^ (r & 7);
            gl_lds16(&Wt[(size_t)(n0 + r) * K + k0 + g * 8], BsF + p * 2048 + wofs);
        }
        __syncthreads();
        short8 af[2][4], bfr[2][4];
        #pragma unroll
        for (int k1 = 0; k1 < 2; k1++) {
            #pragma unroll
            for (int i = 0; i < 4; i++) {
                int r = wm * 64 + i * 16 + lrow;
                int q = (k1 * 4 + quad) ^ (r & 7);
                af[k1][i] = *(const short8*)&As[r][q * 8];
            }
            #pragma unroll
            for (int j = 0; j < 4; j++) {
                int r = wn * 64 + j * 16 + lrow;
                int q = (k1 * 4 + quad) ^ (r & 7);
                bfr[k1][j] = *(const short8*)&Bs[r][q * 8];
            }
        }
        #pragma unroll
        for (int k1 = 0; k1 < 2; k1++)
            #pragma unroll
            for (int i = 0; i < 4; i++)
                #pragma unroll
                for (int j = 0; j < 4; j++)
                    acc[i][j] = __builtin_amdgcn_mfma_f32_16x16x32_bf16(af[k1][i], bfr[k1][j], acc[i][j], 0, 0, 0);
        __syncthreads();
    }
    // epilogue: per-row sum of (x - (acc+b2))^2
    for (int i = 0; i < 4; i++) {
        for (int r = 0; r < 4; r++) {
            int row = m0 + wm * 64 + i * 16 + quad * 4 + r;
            float ns = 0.0f, ds = 0.0f;
            for (int j = 0; j < 4; j++) {
                int col = n0 + wn * 64 + j * 16 + lrow;
                float recon = acc[i][j][r] + b2[col];
                float xv = x[(size_t)row * Ndim + col];
                if (xv != 0.0f) {
                    float d = xv - recon;
                    ns += d * d;
                    ds += 1.0f;
                }
            }
            for (int s = 1; s < 16; s <<= 1) {
                ns += __shfl_xor(ns, s);
                ds += __shfl_xor(ds, s);
            }
            if (lrow == 0) {
                atomicAdd(&num[row], ns);
                atomicAdd(&den[row], ds);
            }
        }
    }
}

// ---------------- LayerNorm over D (fallback path) ----------------
__global__ void ln_kernel(const ushort* __restrict__ enc, const float* __restrict__ gamma,
                          const float* __restrict__ beta, float* __restrict__ out) {
    int row = blockIdx.x;
    int t = threadIdx.x;
    const ushort* e = &enc[(size_t)row * Ddim];
    uint2 u = *(const uint2*)&e[t * 4];
    float v0 = bf2f((ushort)(u.x & 0xFFFF)), v1 = bf2f((ushort)(u.x >> 16));
    float v2 = bf2f((ushort)(u.y & 0xFFFF)), v3 = bf2f((ushort)(u.y >> 16));
    float s = v0 + v1 + v2 + v3;
    float sq = v0 * v0 + v1 * v1 + v2 * v2 + v3 * v3;
    for (int sft = 1; sft < 64; sft <<= 1) {
        s += __shfl_xor(s, sft);
        sq += __shfl_xor(sq, sft);
    }
    __shared__ float red[8];
    int w = t >> 6, lane = t & 63;
    if (lane == 0) { red[w] = s; red[w + 4] = sq; }
    __syncthreads();
    s = red[0] + red[1] + red[2] + red[3];
    sq = red[4] + red[5] + red[6] + red[7];
    float mu = s * (1.0f / Ddim);
    float var = sq * (1.0f / Ddim) - mu * mu;
    float rstd = rsqrtf(var + 1e-5f);
    float4 g = *(const float4*)&gamma[t * 4];
    float4 b = *(const float4*)&beta[t * 4];
    float4 o;
    o.x = (v0 - mu) * rstd * g.x + b.x;
    o.y = (v1 - mu) * rstd * g.y + b.y;
    o.z = (v2 - mu) * rstd * g.z + b.z;
    o.w = (v3 - mu) * rstd * g.w + b.w;
    *(float4*)&out[(size_t)row * Ddim + t * 4] = o;
}

// ---------------- loss = sum_b num[b]/den[b] ----------------
__global__ void loss_final_kernel(const float* __restrict__ num, const float* __restrict__ den,
                                  float* __restrict__ out) {
    int t = threadIdx.x;
    float s = 0.0f;
    for (int i = t; i < Bdim; i += 256) s += num[i] / den[i];
    for (int sft = 1; sft < 64; sft <<= 1) s += __shfl_xor(s, sft);
    __shared__ float red[4];
    int w = t >> 6, lane = t & 63;
    if (lane == 0) red[w] = s;
    __syncthreads();
    if (t == 0) out[0] = red[0] + red[1] + red[2] + red[3];
}

// ---------------- workspace layout ----------------
#define WB_OFF   0ull
#define WB_SZ    ((size_t)Ddim * Ndim * 2)            // 16 MiB
#define WT_OFF   (WB_OFF + WB_SZ)
#define WT_SZ    ((size_t)Ndim * Ddim * 2)            // 16 MiB
#define ENC_OFF  (WT_OFF + WT_SZ)
#define ENC_SZ   ((size_t)Bdim * Ddim * 2)            // 8 MiB
#define NUM_OFF  (ENC_OFF + ENC_SZ)
#define NUM_SZ   ((size_t)Bdim * 4)
#define DEN_OFF  (NUM_OFF + NUM_SZ)
#define DEN_SZ   ((size_t)Bdim * 4)
#define H_OFF    (DEN_OFF + DEN_SZ)
#define H_SZ     ((size_t)Bdim * Ndim * 2)            // 64 MiB
#define FAST_NEED (H_OFF + H_SZ)
#define PART_OFF FAST_NEED
#define PART_SZ  ((size_t)SPLITK * Bdim * Ddim * 4)   // 64 MiB
#define SPLIT_NEED (PART_OFF + PART_SZ)

extern "C" void kernel_launch(void* const* d_in, const int* in_sizes, int n_in,
                              void* d_out, int out_size, void* d_ws, size_t ws_size,
                              hipStream_t stream) {
    const float* x     = (const float*)d_in[0];
    const float* mask  = (const float*)d_in[1];
    const float* W     = (const float*)d_in[2];
    const float* b1    = (const float*)d_in[3];
    const float* b2    = (const float*)d_in[4];
    const float* gamma = (const float*)d_in[5];
    const float* beta  = (const float*)d_in[6];

    float* final_out = (float*)d_out;                       // [B*D]
    float* loss_out  = final_out + (size_t)Bdim * Ddim;     // [1]

    char* ws = (char*)d_ws;
    ushort* Wb   = (ushort*)(ws + WB_OFF);
    ushort* Wt   = (ushort*)(ws + WT_OFF);
    ushort* enc  = (ushort*)(ws + ENC_OFF);
    float*  num  = (float*)(ws + NUM_OFF);
    float*  den  = (float*)(ws + DEN_OFF);
    ushort* hbuf = (ushort*)(ws + H_OFF);
    float*  part = (float*)(ws + PART_OFF);

    hipMemsetAsync(num, 0, NUM_SZ + DEN_SZ, stream);

    prep_w_kernel<<<dim3(Ndim / 64, Ddim / 64), dim3(64, 4), 0, stream>>>(W, Wb, Wt);

    if (ws_size >= SPLIT_NEED) {
        prep_h_kernel<<<(Bdim * (size_t)Ndim) / 8 / 256, 256, 0, stream>>>(x, mask, hbuf);
        gemm1_sk_kernel<<<dim3(Ddim / 128, Bdim / 128, SPLITK), 256, 0, stream>>>(hbuf, Wb, part);
        reduce_ln_kernel<<<Bdim, 256, 0, stream>>>(part, b1, gamma, beta, enc, final_out);
    } else if (ws_size >= FAST_NEED) {
        prep_h_kernel<<<(Bdim * (size_t)Ndim) / 8 / 256, 256, 0, stream>>>(x, mask, hbuf);
        gemm1_kernel<<<dim3(Ddim / 64, Bdim / 128), 256, 0, stream>>>(hbuf, Wb, b1, enc);
        ln_kernel<<<Bdim, 256, 0, stream>>>(enc, gamma, beta, final_out);
    } else {
        gemm1_conv_kernel<<<dim3(Ddim / 64, Bdim / 128), 256, 0, stream>>>(x, mask, Wb, b1, enc);
        ln_kernel<<<Bdim, 256, 0, stream>>>(enc, gamma, beta, final_out);
    }

    gemm2_kernel<<<dim3(Ndim / 128, Bdim / 128), 256, 0, stream>>>(enc, Wt, b2, x, num, den);

    loss_final_kernel<<<1, 256, 0, stream>>>(num, den, loss_out);
}